// Round 3
// baseline (1055.896 us; speedup 1.0000x reference)
//
#include <hip/hip_runtime.h>
#include <hip/hip_bf16.h>

typedef unsigned short u16;
typedef unsigned int u32;

// ---------------- embedding gather: x[tok][d] = emb[ids[tok]][d] ----
__global__ void embed_kernel(const int* __restrict__ ids, const float* __restrict__ emb,
                             float* __restrict__ x) {
  int tok = blockIdx.x, d = threadIdx.x;
  x[tok * 256 + d] = emb[(size_t)ids[tok] * 256 + d];
}

// ---------------- fp32 tiled GEMM: C = act(A[M,K] @ W[N,K]^T + bias) -----------
// block 256, tile 64x64, 4x4 per thread. M%64==0, N%64==0, K%16==0.
template <int ACT>
__global__ __launch_bounds__(256) void gemm_kernel(const float* __restrict__ A,
    const float* __restrict__ W, const float* __restrict__ bias, float* __restrict__ C,
    int M, int N, int K) {
  __shared__ float As[16][68];
  __shared__ float Ws[16][68];
  const int t = threadIdx.x;
  const int m0 = blockIdx.x * 64, n0 = blockIdx.y * 64;
  const int tn = t & 15, tm = t >> 4;
  const int lr = t >> 2, lk = (t & 3) * 4;
  float acc[4][4] = {};
  for (int k0 = 0; k0 < K; k0 += 16) {
    float4 av = *(const float4*)(A + (size_t)(m0 + lr) * K + k0 + lk);
    float4 wv = *(const float4*)(W + (size_t)(n0 + lr) * K + k0 + lk);
    As[lk + 0][lr] = av.x; As[lk + 1][lr] = av.y; As[lk + 2][lr] = av.z; As[lk + 3][lr] = av.w;
    Ws[lk + 0][lr] = wv.x; Ws[lk + 1][lr] = wv.y; Ws[lk + 2][lr] = wv.z; Ws[lk + 3][lr] = wv.w;
    __syncthreads();
#pragma unroll
    for (int kk = 0; kk < 16; ++kk) {
      float4 a = *(const float4*)&As[kk][tm * 4];
      float4 w4 = *(const float4*)&Ws[kk][tn * 4];
      acc[0][0] += a.x * w4.x; acc[0][1] += a.x * w4.y; acc[0][2] += a.x * w4.z; acc[0][3] += a.x * w4.w;
      acc[1][0] += a.y * w4.x; acc[1][1] += a.y * w4.y; acc[1][2] += a.y * w4.z; acc[1][3] += a.y * w4.w;
      acc[2][0] += a.z * w4.x; acc[2][1] += a.z * w4.y; acc[2][2] += a.z * w4.z; acc[2][3] += a.z * w4.w;
      acc[3][0] += a.w * w4.x; acc[3][1] += a.w * w4.y; acc[3][2] += a.w * w4.z; acc[3][3] += a.w * w4.w;
    }
    __syncthreads();
  }
#pragma unroll
  for (int i = 0; i < 4; ++i) {
    int row = m0 + tm * 4 + i;
    float4 o;
    float* po = (float*)&o;
#pragma unroll
    for (int j = 0; j < 4; ++j) {
      int col = n0 + tn * 4 + j;
      float v = acc[i][j] + bias[col];
      if (ACT == 1) v = fmaxf(v, 0.f);
      if (ACT == 2) v = 0.5f * v * (1.f + erff(v * 0.70710678118654752f));
      po[j] = v;
    }
    *(float4*)(C + (size_t)row * N + n0 + tn * 4) = o;
  }
}

// ---------------- split-K partial GEMM (no bias/act): Cpart[kz] = A@W^T over K-slice
__global__ __launch_bounds__(256) void gemm_part_kernel(const float* __restrict__ A,
    const float* __restrict__ W, float* __restrict__ Cpart, int M, int N, int K, int KS) {
  __shared__ float As[16][68];
  __shared__ float Ws[16][68];
  const int t = threadIdx.x;
  const int m0 = blockIdx.x * 64, n0 = blockIdx.y * 64;
  const int kz = blockIdx.z;
  const int tn = t & 15, tm = t >> 4;
  const int lr = t >> 2, lk = (t & 3) * 4;
  float acc[4][4] = {};
  const int kend = kz * KS + KS;
  for (int k0 = kz * KS; k0 < kend; k0 += 16) {
    float4 av = *(const float4*)(A + (size_t)(m0 + lr) * K + k0 + lk);
    float4 wv = *(const float4*)(W + (size_t)(n0 + lr) * K + k0 + lk);
    As[lk + 0][lr] = av.x; As[lk + 1][lr] = av.y; As[lk + 2][lr] = av.z; As[lk + 3][lr] = av.w;
    Ws[lk + 0][lr] = wv.x; Ws[lk + 1][lr] = wv.y; Ws[lk + 2][lr] = wv.z; Ws[lk + 3][lr] = wv.w;
    __syncthreads();
#pragma unroll
    for (int kk = 0; kk < 16; ++kk) {
      float4 a = *(const float4*)&As[kk][tm * 4];
      float4 w4 = *(const float4*)&Ws[kk][tn * 4];
      acc[0][0] += a.x * w4.x; acc[0][1] += a.x * w4.y; acc[0][2] += a.x * w4.z; acc[0][3] += a.x * w4.w;
      acc[1][0] += a.y * w4.x; acc[1][1] += a.y * w4.y; acc[1][2] += a.y * w4.z; acc[1][3] += a.y * w4.w;
      acc[2][0] += a.z * w4.x; acc[2][1] += a.z * w4.y; acc[2][2] += a.z * w4.z; acc[2][3] += a.z * w4.w;
      acc[3][0] += a.w * w4.x; acc[3][1] += a.w * w4.y; acc[3][2] += a.w * w4.z; acc[3][3] += a.w * w4.w;
    }
    __syncthreads();
  }
  float* Cz = Cpart + (size_t)kz * M * N;
#pragma unroll
  for (int i = 0; i < 4; ++i) {
    int row = m0 + tm * 4 + i;
    float4 o;
    o.x = acc[i][0]; o.y = acc[i][1]; o.z = acc[i][2]; o.w = acc[i][3];
    *(float4*)(Cz + (size_t)row * N + n0 + tn * 4) = o;
  }
}

// ---------------- reduce parts + bias + activation -> dst ----
template <int ACT>
__global__ void red_bias_act_kernel(const float* __restrict__ parts, int nparts, int pstride,
                                    const float* __restrict__ bias, float* __restrict__ dst, int N) {
  int idx = blockIdx.x * 256 + threadIdx.x;
  float v = bias[idx % N];
  for (int p = 0; p < nparts; ++p) v += parts[(size_t)p * pstride + idx];
  if (ACT == 1) v = fmaxf(v, 0.f);
  if (ACT == 2) v = 0.5f * v * (1.f + erff(v * 0.70710678118654752f));
  dst[idx] = v;
}

// ---------------- attention: one wave per query; K xor-swizzled in LDS, V natural ---
__global__ __launch_bounds__(256) void attn_kernel(const float* __restrict__ qkv,
    const int* __restrict__ mask, float* __restrict__ o) {
  __shared__ float Klds[8192];
  __shared__ float Vlds[8192];
  const int blk = blockIdx.x;                 // 512 = 4b * 4h * 32 qgroups
  const int b = blk >> 7, h = (blk >> 5) & 3, qg = blk & 31;
  const int t = threadIdx.x;
  for (int i = t; i < 8192; i += 256) {
    int s = i >> 6, d = i & 63;
    size_t base = (size_t)(b * 128 + s) * 768 + h * 64 + d;
    Klds[(s << 6) + (d ^ (s & 31))] = qkv[base + 256];
    Vlds[i] = qkv[base + 512];
  }
  __syncthreads();
  const int wave = t >> 6, lane = t & 63;
  const int q = qg * 4 + wave;
  float qv = qkv[(size_t)(b * 128 + q) * 768 + h * 64 + lane];
  const int m0i = mask[b * 128 + lane];
  const int m1i = mask[b * 128 + 64 + lane];
  float s0 = 0.f, s1 = 0.f;
  const int sw = lane & 31;
  for (int d = 0; d < 64; ++d) {
    float qd = __shfl(qv, d);
    s0 += qd * Klds[(lane << 6) + (d ^ sw)];
    s1 += qd * Klds[((lane + 64) << 6) + (d ^ sw)];
  }
  s0 *= 0.125f; s1 *= 0.125f;
  if (m0i == 0) s0 = -1000000000.0f;
  if (m1i == 0) s1 = -1000000000.0f;
  float m = fmaxf(s0, s1);
  for (int off = 32; off; off >>= 1) m = fmaxf(m, __shfl_xor(m, off));
  float p0 = expf(s0 - m), p1 = expf(s1 - m);
  float sum = p0 + p1;
  for (int off = 32; off; off >>= 1) sum += __shfl_xor(sum, off);
  float rs = 1.f / sum;
  float acc = 0.f;
  for (int k = 0; k < 64; ++k) acc += __shfl(p0, k) * Vlds[(k << 6) + lane];
  for (int k = 0; k < 64; ++k) acc += __shfl(p1, k) * Vlds[((k + 64) << 6) + lane];
  o[(size_t)(b * 128 + q) * 256 + h * 64 + lane] = acc * rs;
}

// ---------------- residual + split-K reduce + bias + LayerNorm (in-place on x) ----
__global__ __launch_bounds__(256) void add_ln_red_kernel(float* __restrict__ x,
    const float* __restrict__ parts, int nparts, int pstride, const float* __restrict__ bias,
    const float* __restrict__ g, const float* __restrict__ b) {
  int tok = blockIdx.x, t = threadIdx.x;
  int idx = tok * 256 + t;
  float r = x[idx] + bias[t];
  for (int p = 0; p < nparts; ++p) r += parts[(size_t)p * pstride + idx];
  float s = r, sq = r * r;
  for (int off = 32; off; off >>= 1) { s += __shfl_xor(s, off); sq += __shfl_xor(sq, off); }
  __shared__ float red[8];
  int wave = t >> 6, lane = t & 63;
  if (lane == 0) { red[wave] = s; red[4 + wave] = sq; }
  __syncthreads();
  float S = red[0] + red[1] + red[2] + red[3];
  float SQ = red[4] + red[5] + red[6] + red[7];
  float mean = S * (1.f / 256.f);
  float var = SQ * (1.f / 256.f) - mean * mean;
  float inv = 1.f / sqrtf(fmaxf(var, 0.f) + 1e-5f);
  x[idx] = (r - mean) * inv * g[t] + b[t];
}

// ---------------- masked mean pool -> pooled[4][256] ----------------
__global__ void pool_kernel(const float* __restrict__ x, const int* __restrict__ mask,
                            float* __restrict__ pooled) {
  int b = blockIdx.x, d = threadIdx.x;
  float s = 0.f, c = 0.f;
  for (int ss = 0; ss < 128; ++ss) {
    float m = (float)mask[b * 128 + ss];
    s += m * x[(size_t)(b * 128 + ss) * 256 + d];
    c += m;
  }
  pooled[b * 256 + d] = s / fmaxf(c, 1.f);
}

// ---------------- projection GEMV: pe[b][r] = pooled[b] . proj_w[r] + proj_b[r] ----
// block 256 = 4 waves; each half-wave (32 lanes) owns one row; 8 rows/block.
__global__ __launch_bounds__(256) void proj_kernel(const float* __restrict__ pooled,
    const float* __restrict__ W, const float* __restrict__ bias, float* __restrict__ pe) {
  __shared__ float pl[1024];
  int t = threadIdx.x;
  for (int i = t; i < 1024; i += 256) pl[i] = pooled[i];
  __syncthreads();
  int wave = t >> 6, lane = t & 63;
  int half = lane >> 5, sl = lane & 31;
  int row = blockIdx.x * 8 + wave * 2 + half;
  float4 w0 = *(const float4*)(W + (size_t)row * 256 + sl * 8);
  float4 w1 = *(const float4*)(W + (size_t)row * 256 + sl * 8 + 4);
  float a0, a1, a2, a3;
#pragma unroll
  for (int bb = 0; bb < 4; ++bb) {
    const float* pp = &pl[bb * 256 + sl * 8];
    float v = w0.x * pp[0] + w0.y * pp[1] + w0.z * pp[2] + w0.w * pp[3]
            + w1.x * pp[4] + w1.y * pp[5] + w1.z * pp[6] + w1.w * pp[7];
    if (bb == 0) a0 = v; else if (bb == 1) a1 = v; else if (bb == 2) a2 = v; else a3 = v;
  }
#pragma unroll
  for (int off = 1; off < 32; off <<= 1) {
    a0 += __shfl_xor(a0, off); a1 += __shfl_xor(a1, off);
    a2 += __shfl_xor(a2, off); a3 += __shfl_xor(a3, off);
  }
  if (sl == 0) {
    float bv = bias[row];
    pe[0 * 114688 + row] = a0 + bv;
    pe[1 * 114688 + row] = a1 + bv;
    pe[2 * 114688 + row] = a2 + bv;
    pe[3 * 114688 + row] = a3 + bv;
  }
}

// ---------------- tile_A: out[b,i,r,c] = Abase[b,p(i),r,c&63] * sa[p] (fp32 out) ----
__global__ __launch_bounds__(256) void tile_a_kernel(const float* __restrict__ Abase,
    const float* __restrict__ scales, float* __restrict__ out, int nI, int ind,
    int pdiv, int pmul, int padd) {
  int row = blockIdx.x;                 // ((b*nI+i)*16 + r)
  int r = row & 15, bi = row >> 4;
  int i = bi % nI, b = bi / nI;
  int p = (i / pdiv) * 7 + (i % pdiv) * pmul + padd;
  float s = scales[2 * p];
  __shared__ float chunk[64];
  int t = threadIdx.x;
  if (t < 64) chunk[t] = Abase[((size_t)(b * 224 + p) * 16 + r) * 64 + t] * s;
  __syncthreads();
  size_t ob = (size_t)row * ind;
  for (int u = t; u * 4 < ind; u += 256) {
    int c0 = u * 4;
    float4 ov = *(const float4*)&chunk[c0 & 63];
    *(float4*)(out + ob + c0) = ov;
  }
}

// ---------------- tile_B: out[b,i,c,r] = Bbase[b,p(i),c&63,r] * sb[p] (fp32 out) ----
__global__ __launch_bounds__(256) void tile_b_kernel(const float* __restrict__ Bbase,
    const float* __restrict__ scales, float* __restrict__ out, int nI, int ind, int nchunks,
    int pdiv, int pmul, int padd) {
  int blk = blockIdx.x;
  int cc = blk % nchunks, bi = blk / nchunks;
  int i = bi % nI, b = bi / nI;
  int p = (i / pdiv) * 7 + (i % pdiv) * pmul + padd;
  float s = scales[2 * p + 1];
  __shared__ float chunk[1024];
  int t = threadIdx.x;
  for (int e = t; e < 1024; e += 256) chunk[e] = Bbase[(size_t)(b * 224 + p) * 1024 + e] * s;
  __syncthreads();
  int cchunk16 = (ind / nchunks) * 16;
  size_t ob = (size_t)bi * ind * 16 + (size_t)cc * cchunk16;
  for (int u = t; u * 4 < cchunk16; u += 256) {
    int e0 = u * 4;
    int cabs = (cc * cchunk16 + e0) >> 4;
    int src = ((cabs & 63) << 4) + (e0 & 15);
    float4 ov = *(const float4*)&chunk[src];
    *(float4*)(out + ob + e0) = ov;
  }
}

extern "C" void kernel_launch(void* const* d_in, const int* in_sizes, int n_in,
                              void* d_out, int out_size, void* d_ws, size_t ws_size,
                              hipStream_t stream) {
  const int* ids     = (const int*)d_in[0];
  const int* mask    = (const int*)d_in[1];
  const float* emb   = (const float*)d_in[2];
  const float* qkv_w = (const float*)d_in[3];
  const float* qkv_b = (const float*)d_in[4];
  const float* out_w = (const float*)d_in[5];
  const float* out_b = (const float*)d_in[6];
  const float* ln1_g = (const float*)d_in[7];
  const float* ln1_b = (const float*)d_in[8];
  const float* ff1_w = (const float*)d_in[9];
  const float* ff1_b = (const float*)d_in[10];
  const float* ff2_w = (const float*)d_in[11];
  const float* ff2_b = (const float*)d_in[12];
  const float* ln2_g = (const float*)d_in[13];
  const float* ln2_b = (const float*)d_in[14];
  const float* proj_w = (const float*)d_in[15];
  const float* proj_b = (const float*)d_in[16];
  const float* a1_w = (const float*)d_in[17];
  const float* a1_b = (const float*)d_in[18];
  const float* a2_w = (const float*)d_in[19];
  const float* a2_b = (const float*)d_in[20];
  const float* b1_w = (const float*)d_in[21];
  const float* b1_b = (const float*)d_in[22];
  const float* b2_w = (const float*)d_in[23];
  const float* b2_b = (const float*)d_in[24];
  const float* scales = (const float*)d_in[25];

  float* w = (float*)d_ws;
  float* x      = w + 0;        // 512*256
  float* qkv    = w + 262144;   // 512*768
  float* attn_o = w + 655360;   // 512*256
  float* ff     = w + 786432;   // 512*2048
  float* pooled = w + 1835008;  // 4*256
  float* pe     = w + 1836032;  // 896*512
  float* hA     = w + 2294784;  // 896*256
  float* hB     = w + 2524160;  // 896*256
  float* Abase  = w + 2753536;  // 896*1024
  float* Bbase  = w + 3671040;  // 896*1024
  float* parts  = w + 4588544;  // up to 8*131072 (reused scratch)

  float* out = (float*)d_out;

  embed_kernel<<<512, 256, 0, stream>>>(ids, emb, x);
  for (int l = 0; l < 3; ++l) {
    gemm_kernel<0><<<dim3(8, 12), 256, 0, stream>>>(x, qkv_w + l * 768 * 256, qkv_b + l * 768,
                                                    qkv, 512, 768, 256);
    attn_kernel<<<512, 256, 0, stream>>>(qkv, mask, attn_o);
    gemm_part_kernel<<<dim3(8, 4, 4), 256, 0, stream>>>(attn_o, out_w + l * 256 * 256, parts,
                                                        512, 256, 256, 64);
    add_ln_red_kernel<<<512, 256, 0, stream>>>(x, parts, 4, 131072, out_b + l * 256,
                                               ln1_g + l * 256, ln1_b + l * 256);
    gemm_kernel<1><<<dim3(8, 32), 256, 0, stream>>>(x, ff1_w + l * 2048 * 256, ff1_b + l * 2048,
                                                    ff, 512, 2048, 256);
    gemm_part_kernel<<<dim3(8, 4, 8), 256, 0, stream>>>(ff, ff2_w + l * 256 * 2048, parts,
                                                        512, 256, 2048, 256);
    add_ln_red_kernel<<<512, 256, 0, stream>>>(x, parts, 8, 131072, ff2_b + l * 256,
                                               ln2_g + l * 256, ln2_b + l * 256);
  }
  pool_kernel<<<4, 256, 0, stream>>>(x, mask, pooled);
  proj_kernel<<<14336, 256, 0, stream>>>(pooled, proj_w, proj_b, pe);

  gemm_part_kernel<<<dim3(14, 4, 4), 256, 0, stream>>>(pe, a1_w, parts, 896, 256, 512, 128);
  red_bias_act_kernel<2><<<896, 256, 0, stream>>>(parts, 4, 229376, a1_b, hA, 256);
  gemm_kernel<0><<<dim3(14, 16), 256, 0, stream>>>(hA, a2_w, a2_b, Abase, 896, 1024, 256);

  gemm_part_kernel<<<dim3(14, 4, 4), 256, 0, stream>>>(pe, b1_w, parts, 896, 256, 512, 128);
  red_bias_act_kernel<2><<<896, 256, 0, stream>>>(parts, 4, 229376, b1_b, hB, 256);
  gemm_kernel<0><<<dim3(14, 16), 256, 0, stream>>>(hB, b2_w, b2_b, Bbase, 896, 1024, 256);

  // outputs (flat offsets in elements):
  // out0 A_HID (4,192,16,4096)  @ 0
  // out1 A_INT (4, 32,16,11008) @ 50331648
  // out2 B_HID (4, 96,4096,16)  @ 72876032
  // out3 B_KV  (4, 64,1024,16)  @ 98041856
  // out4 B_INT (4, 64,11008,16) @ 102236160
  tile_a_kernel<<<12288, 256, 0, stream>>>(Abase, scales, out, 192, 4096, 6, 1, 0);
  tile_a_kernel<<<2048, 256, 0, stream>>>(Abase, scales, out + 50331648ull, 32, 11008, 1, 0, 6);
  tile_b_kernel<<<3072, 256, 0, stream>>>(Bbase, scales, out + 72876032ull, 96, 4096, 8, 3, 3, 0);
  tile_b_kernel<<<512, 256, 0, stream>>>(Bbase, scales, out + 98041856ull, 64, 1024, 2, 2, 1, 1);
  tile_b_kernel<<<2048, 256, 0, stream>>>(Bbase, scales, out + 102236160ull, 64, 11008, 8, 2, 1, 4);
}

// Round 4
// 974.256 us; speedup vs baseline: 1.0838x; 1.0838x over previous
//
#include <hip/hip_runtime.h>
#include <hip/hip_bf16.h>

typedef unsigned short u16;
typedef unsigned int u32;
typedef __attribute__((ext_vector_type(8))) short short8;
typedef __attribute__((ext_vector_type(4))) float floatx4;

__device__ __forceinline__ u16 f2bf(float f) {
  u32 x = __float_as_uint(f);
  x += 0x7FFFu + ((x >> 16) & 1u);
  return (u16)(x >> 16);
}
__device__ __forceinline__ u32 pk2(float lo, float hi) {
  return (u32)f2bf(lo) | ((u32)f2bf(hi) << 16);
}

// ---------------- embedding gather: x[tok][d] = emb[ids[tok]][d] ----
__global__ void embed_kernel(const int* __restrict__ ids, const float* __restrict__ emb,
                             float* __restrict__ x) {
  int tok = blockIdx.x, d = threadIdx.x;
  x[tok * 256 + d] = emb[(size_t)ids[tok] * 256 + d];
}

// ---------------- bf16 MFMA GEMM: C = act(A[M,K] @ W[N,K]^T + bias) ------------
// block 256 (4 waves), tile 64x64, K-step 32. fp32 inputs converted to bf16 in
// staging (fp32 accumulate in MFMA). Wave w owns rows w*16..w*16+15, all 4
// 16-col tiles. SPLIT=1: write partial sums to C + kz*pstride (no bias/act).
// A-frag: lane holds A[m=lane&15][k=(lane>>4)*8+j]; B-frag same pattern on W
// (operand B = W^T). C/D: col=lane&15, row=(lane>>4)*4+reg  [guide §3, m89/m91].
template <int ACT, int SPLIT>
__global__ __launch_bounds__(256) void mfma_gemm_kernel(const float* __restrict__ A,
    const float* __restrict__ W, const float* __restrict__ bias, float* __restrict__ C,
    int M, int N, int K, int KS, int pstride) {
  __shared__ u16 Abf[64 * 32];
  __shared__ u16 Wbf[64 * 32];
  const int t = threadIdx.x;
  const int m0 = blockIdx.x * 64, n0 = blockIdx.y * 64;
  const int kz = blockIdx.z;
  const int srow = t >> 2, skc = (t & 3) * 8;   // staging: row 0..63, k-chunk 0/8/16/24
  const int w = t >> 6, lane = t & 63;
  const int q = lane >> 4, rr = lane & 15;
  floatx4 acc[4];
#pragma unroll
  for (int i = 0; i < 4; ++i) acc[i] = (floatx4){0.f, 0.f, 0.f, 0.f};

  const int kbeg = kz * KS, kend = kbeg + KS;
  for (int k0 = kbeg; k0 < kend; k0 += 32) {
    const float* ga = A + (size_t)(m0 + srow) * K + k0 + skc;
    const float* gw = W + (size_t)(n0 + srow) * K + k0 + skc;
    float4 a0 = *(const float4*)ga;
    float4 a1 = *(const float4*)(ga + 4);
    float4 w0 = *(const float4*)gw;
    float4 w1 = *(const float4*)(gw + 4);
    uint4 pa, pw;
    pa.x = pk2(a0.x, a0.y); pa.y = pk2(a0.z, a0.w);
    pa.z = pk2(a1.x, a1.y); pa.w = pk2(a1.z, a1.w);
    pw.x = pk2(w0.x, w0.y); pw.y = pk2(w0.z, w0.w);
    pw.z = pk2(w1.x, w1.y); pw.w = pk2(w1.z, w1.w);
    __syncthreads();
    *(uint4*)&Abf[srow * 32 + skc] = pa;
    *(uint4*)&Wbf[srow * 32 + skc] = pw;
    __syncthreads();
    short8 af = *(short8*)&Abf[(w * 16 + rr) * 32 + q * 8];
#pragma unroll
    for (int ct = 0; ct < 4; ++ct) {
      short8 bf = *(short8*)&Wbf[(ct * 16 + rr) * 32 + q * 8];
      acc[ct] = __builtin_amdgcn_mfma_f32_16x16x32_bf16(af, bf, acc[ct], 0, 0, 0);
    }
  }

  float* dst = SPLIT ? (C + (size_t)kz * pstride) : C;
#pragma unroll
  for (int ct = 0; ct < 4; ++ct) {
    int col = n0 + ct * 16 + rr;
#pragma unroll
    for (int r = 0; r < 4; ++r) {
      int row = m0 + w * 16 + q * 4 + r;
      float v = acc[ct][r];
      if (!SPLIT) {
        v += bias[col];
        if (ACT == 1) v = fmaxf(v, 0.f);
        if (ACT == 2) v = 0.5f * v * (1.f + erff(v * 0.70710678118654752f));
      }
      dst[(size_t)row * N + col] = v;
    }
  }
}

// ---------------- reduce parts + bias + activation -> dst ----
template <int ACT>
__global__ void red_bias_act_kernel(const float* __restrict__ parts, int nparts, int pstride,
                                    const float* __restrict__ bias, float* __restrict__ dst, int N) {
  int idx = blockIdx.x * 256 + threadIdx.x;
  float v = bias[idx % N];
  for (int p = 0; p < nparts; ++p) v += parts[(size_t)p * pstride + idx];
  if (ACT == 1) v = fmaxf(v, 0.f);
  if (ACT == 2) v = 0.5f * v * (1.f + erff(v * 0.70710678118654752f));
  dst[idx] = v;
}

// ---------------- attention: one wave per query; K xor-swizzled in LDS, V natural ---
__global__ __launch_bounds__(256) void attn_kernel(const float* __restrict__ qkv,
    const int* __restrict__ mask, float* __restrict__ o) {
  __shared__ float Klds[8192];
  __shared__ float Vlds[8192];
  const int blk = blockIdx.x;                 // 512 = 4b * 4h * 32 qgroups
  const int b = blk >> 7, h = (blk >> 5) & 3, qg = blk & 31;
  const int t = threadIdx.x;
  for (int i = t; i < 8192; i += 256) {
    int s = i >> 6, d = i & 63;
    size_t base = (size_t)(b * 128 + s) * 768 + h * 64 + d;
    Klds[(s << 6) + (d ^ (s & 31))] = qkv[base + 256];
    Vlds[i] = qkv[base + 512];
  }
  __syncthreads();
  const int wave = t >> 6, lane = t & 63;
  const int q = qg * 4 + wave;
  float qv = qkv[(size_t)(b * 128 + q) * 768 + h * 64 + lane];
  const int m0i = mask[b * 128 + lane];
  const int m1i = mask[b * 128 + 64 + lane];
  float s0 = 0.f, s1 = 0.f;
  const int sw = lane & 31;
  for (int d = 0; d < 64; ++d) {
    float qd = __shfl(qv, d);
    s0 += qd * Klds[(lane << 6) + (d ^ sw)];
    s1 += qd * Klds[((lane + 64) << 6) + (d ^ sw)];
  }
  s0 *= 0.125f; s1 *= 0.125f;
  if (m0i == 0) s0 = -1000000000.0f;
  if (m1i == 0) s1 = -1000000000.0f;
  float m = fmaxf(s0, s1);
  for (int off = 32; off; off >>= 1) m = fmaxf(m, __shfl_xor(m, off));
  float p0 = expf(s0 - m), p1 = expf(s1 - m);
  float sum = p0 + p1;
  for (int off = 32; off; off >>= 1) sum += __shfl_xor(sum, off);
  float rs = 1.f / sum;
  float acc = 0.f;
  for (int k = 0; k < 64; ++k) acc += __shfl(p0, k) * Vlds[(k << 6) + lane];
  for (int k = 0; k < 64; ++k) acc += __shfl(p1, k) * Vlds[((k + 64) << 6) + lane];
  o[(size_t)(b * 128 + q) * 256 + h * 64 + lane] = acc * rs;
}

// ---------------- residual + split-K reduce + bias + LayerNorm (in-place on x) ----
__global__ __launch_bounds__(256) void add_ln_red_kernel(float* __restrict__ x,
    const float* __restrict__ parts, int nparts, int pstride, const float* __restrict__ bias,
    const float* __restrict__ g, const float* __restrict__ b) {
  int tok = blockIdx.x, t = threadIdx.x;
  int idx = tok * 256 + t;
  float r = x[idx] + bias[t];
  for (int p = 0; p < nparts; ++p) r += parts[(size_t)p * pstride + idx];
  float s = r, sq = r * r;
  for (int off = 32; off; off >>= 1) { s += __shfl_xor(s, off); sq += __shfl_xor(sq, off); }
  __shared__ float red[8];
  int wave = t >> 6, lane = t & 63;
  if (lane == 0) { red[wave] = s; red[4 + wave] = sq; }
  __syncthreads();
  float S = red[0] + red[1] + red[2] + red[3];
  float SQ = red[4] + red[5] + red[6] + red[7];
  float mean = S * (1.f / 256.f);
  float var = SQ * (1.f / 256.f) - mean * mean;
  float inv = 1.f / sqrtf(fmaxf(var, 0.f) + 1e-5f);
  x[idx] = (r - mean) * inv * g[t] + b[t];
}

// ---------------- masked mean pool -> pooled[4][256] ----------------
__global__ void pool_kernel(const float* __restrict__ x, const int* __restrict__ mask,
                            float* __restrict__ pooled) {
  int b = blockIdx.x, d = threadIdx.x;
  float s = 0.f, c = 0.f;
  for (int ss = 0; ss < 128; ++ss) {
    float m = (float)mask[b * 128 + ss];
    s += m * x[(size_t)(b * 128 + ss) * 256 + d];
    c += m;
  }
  pooled[b * 256 + d] = s / fmaxf(c, 1.f);
}

// ---------------- projection GEMV: pe[b][r] = pooled[b] . proj_w[r] + proj_b[r] ----
__global__ __launch_bounds__(256) void proj_kernel(const float* __restrict__ pooled,
    const float* __restrict__ W, const float* __restrict__ bias, float* __restrict__ pe) {
  __shared__ float pl[1024];
  int t = threadIdx.x;
  for (int i = t; i < 1024; i += 256) pl[i] = pooled[i];
  __syncthreads();
  int wave = t >> 6, lane = t & 63;
  int half = lane >> 5, sl = lane & 31;
  int row = blockIdx.x * 8 + wave * 2 + half;
  float4 w0 = *(const float4*)(W + (size_t)row * 256 + sl * 8);
  float4 w1 = *(const float4*)(W + (size_t)row * 256 + sl * 8 + 4);
  float a0, a1, a2, a3;
#pragma unroll
  for (int bb = 0; bb < 4; ++bb) {
    const float* pp = &pl[bb * 256 + sl * 8];
    float v = w0.x * pp[0] + w0.y * pp[1] + w0.z * pp[2] + w0.w * pp[3]
            + w1.x * pp[4] + w1.y * pp[5] + w1.z * pp[6] + w1.w * pp[7];
    if (bb == 0) a0 = v; else if (bb == 1) a1 = v; else if (bb == 2) a2 = v; else a3 = v;
  }
#pragma unroll
  for (int off = 1; off < 32; off <<= 1) {
    a0 += __shfl_xor(a0, off); a1 += __shfl_xor(a1, off);
    a2 += __shfl_xor(a2, off); a3 += __shfl_xor(a3, off);
  }
  if (sl == 0) {
    float bv = bias[row];
    pe[0 * 114688 + row] = a0 + bv;
    pe[1 * 114688 + row] = a1 + bv;
    pe[2 * 114688 + row] = a2 + bv;
    pe[3 * 114688 + row] = a3 + bv;
  }
}

// ---------------- tile_A: out[b,i,r,c] = Abase[b,p(i),r,c&63] * sa[p] (fp32 out) ----
__global__ __launch_bounds__(256) void tile_a_kernel(const float* __restrict__ Abase,
    const float* __restrict__ scales, float* __restrict__ out, int nI, int ind,
    int pdiv, int pmul, int padd) {
  int row = blockIdx.x;                 // ((b*nI+i)*16 + r)
  int r = row & 15, bi = row >> 4;
  int i = bi % nI, b = bi / nI;
  int p = (i / pdiv) * 7 + (i % pdiv) * pmul + padd;
  float s = scales[2 * p];
  __shared__ float chunk[64];
  int t = threadIdx.x;
  if (t < 64) chunk[t] = Abase[((size_t)(b * 224 + p) * 16 + r) * 64 + t] * s;
  __syncthreads();
  size_t ob = (size_t)row * ind;
  for (int u = t; u * 4 < ind; u += 256) {
    int c0 = u * 4;
    float4 ov = *(const float4*)&chunk[c0 & 63];
    *(float4*)(out + ob + c0) = ov;
  }
}

// ---------------- tile_B: out[b,i,c,r] = Bbase[b,p(i),c&63,r] * sb[p] (fp32 out) ----
__global__ __launch_bounds__(256) void tile_b_kernel(const float* __restrict__ Bbase,
    const float* __restrict__ scales, float* __restrict__ out, int nI, int ind, int nchunks,
    int pdiv, int pmul, int padd) {
  int blk = blockIdx.x;
  int cc = blk % nchunks, bi = blk / nchunks;
  int i = bi % nI, b = bi / nI;
  int p = (i / pdiv) * 7 + (i % pdiv) * pmul + padd;
  float s = scales[2 * p + 1];
  __shared__ float chunk[1024];
  int t = threadIdx.x;
  for (int e = t; e < 1024; e += 256) chunk[e] = Bbase[(size_t)(b * 224 + p) * 1024 + e] * s;
  __syncthreads();
  int cchunk16 = (ind / nchunks) * 16;
  size_t ob = (size_t)bi * ind * 16 + (size_t)cc * cchunk16;
  for (int u = t; u * 4 < cchunk16; u += 256) {
    int e0 = u * 4;
    int cabs = (cc * cchunk16 + e0) >> 4;
    int src = ((cabs & 63) << 4) + (e0 & 15);
    float4 ov = *(const float4*)&chunk[src];
    *(float4*)(out + ob + e0) = ov;
  }
}

extern "C" void kernel_launch(void* const* d_in, const int* in_sizes, int n_in,
                              void* d_out, int out_size, void* d_ws, size_t ws_size,
                              hipStream_t stream) {
  const int* ids     = (const int*)d_in[0];
  const int* mask    = (const int*)d_in[1];
  const float* emb   = (const float*)d_in[2];
  const float* qkv_w = (const float*)d_in[3];
  const float* qkv_b = (const float*)d_in[4];
  const float* out_w = (const float*)d_in[5];
  const float* out_b = (const float*)d_in[6];
  const float* ln1_g = (const float*)d_in[7];
  const float* ln1_b = (const float*)d_in[8];
  const float* ff1_w = (const float*)d_in[9];
  const float* ff1_b = (const float*)d_in[10];
  const float* ff2_w = (const float*)d_in[11];
  const float* ff2_b = (const float*)d_in[12];
  const float* ln2_g = (const float*)d_in[13];
  const float* ln2_b = (const float*)d_in[14];
  const float* proj_w = (const float*)d_in[15];
  const float* proj_b = (const float*)d_in[16];
  const float* a1_w = (const float*)d_in[17];
  const float* a1_b = (const float*)d_in[18];
  const float* a2_w = (const float*)d_in[19];
  const float* a2_b = (const float*)d_in[20];
  const float* b1_w = (const float*)d_in[21];
  const float* b1_b = (const float*)d_in[22];
  const float* b2_w = (const float*)d_in[23];
  const float* b2_b = (const float*)d_in[24];
  const float* scales = (const float*)d_in[25];

  float* w = (float*)d_ws;
  float* x      = w + 0;        // 512*256
  float* qkv    = w + 262144;   // 512*768
  float* attn_o = w + 655360;   // 512*256
  float* ff     = w + 786432;   // 512*2048
  float* pooled = w + 1835008;  // 4*256
  float* pe     = w + 1836032;  // 896*512
  float* hA     = w + 2294784;  // 896*256
  float* hB     = w + 2524160;  // 896*256
  float* Abase  = w + 2753536;  // 896*1024
  float* Bbase  = w + 3671040;  // 896*1024
  float* parts  = w + 4588544;  // up to 8*131072 (reused scratch)

  float* out = (float*)d_out;

  embed_kernel<<<512, 256, 0, stream>>>(ids, emb, x);
  for (int l = 0; l < 3; ++l) {
    mfma_gemm_kernel<0, 0><<<dim3(8, 12), 256, 0, stream>>>(
        x, qkv_w + l * 768 * 256, qkv_b + l * 768, qkv, 512, 768, 256, 256, 0);
    attn_kernel<<<512, 256, 0, stream>>>(qkv, mask, attn_o);
    mfma_gemm_kernel<0, 1><<<dim3(8, 4, 4), 256, 0, stream>>>(
        attn_o, out_w + l * 256 * 256, nullptr, parts, 512, 256, 256, 64, 131072);
    add_ln_red_kernel<<<512, 256, 0, stream>>>(x, parts, 4, 131072, out_b + l * 256,
                                               ln1_g + l * 256, ln1_b + l * 256);
    mfma_gemm_kernel<1, 0><<<dim3(8, 32), 256, 0, stream>>>(
        x, ff1_w + l * 2048 * 256, ff1_b + l * 2048, ff, 512, 2048, 256, 256, 0);
    mfma_gemm_kernel<0, 1><<<dim3(8, 4, 8), 256, 0, stream>>>(
        ff, ff2_w + l * 256 * 2048, nullptr, parts, 512, 256, 2048, 256, 131072);
    add_ln_red_kernel<<<512, 256, 0, stream>>>(x, parts, 8, 131072, ff2_b + l * 256,
                                               ln2_g + l * 256, ln2_b + l * 256);
  }
  pool_kernel<<<4, 256, 0, stream>>>(x, mask, pooled);
  proj_kernel<<<14336, 256, 0, stream>>>(pooled, proj_w, proj_b, pe);

  mfma_gemm_kernel<0, 1><<<dim3(14, 4, 4), 256, 0, stream>>>(
      pe, a1_w, nullptr, parts, 896, 256, 512, 128, 229376);
  red_bias_act_kernel<2><<<896, 256, 0, stream>>>(parts, 4, 229376, a1_b, hA, 256);
  mfma_gemm_kernel<0, 0><<<dim3(14, 16), 256, 0, stream>>>(
      hA, a2_w, a2_b, Abase, 896, 1024, 256, 256, 0);

  mfma_gemm_kernel<0, 1><<<dim3(14, 4, 4), 256, 0, stream>>>(
      pe, b1_w, nullptr, parts, 896, 256, 512, 128, 229376);
  red_bias_act_kernel<2><<<896, 256, 0, stream>>>(parts, 4, 229376, b1_b, hB, 256);
  mfma_gemm_kernel<0, 0><<<dim3(14, 16), 256, 0, stream>>>(
      hB, b2_w, b2_b, Bbase, 896, 1024, 256, 256, 0);

  // outputs (flat offsets in elements):
  // out0 A_HID (4,192,16,4096)  @ 0
  // out1 A_INT (4, 32,16,11008) @ 50331648
  // out2 B_HID (4, 96,4096,16)  @ 72876032
  // out3 B_KV  (4, 64,1024,16)  @ 98041856
  // out4 B_INT (4, 64,11008,16) @ 102236160
  tile_a_kernel<<<12288, 256, 0, stream>>>(Abase, scales, out, 192, 4096, 6, 1, 0);
  tile_a_kernel<<<2048, 256, 0, stream>>>(Abase, scales, out + 50331648ull, 32, 11008, 1, 0, 6);
  tile_b_kernel<<<3072, 256, 0, stream>>>(Bbase, scales, out + 72876032ull, 96, 4096, 8, 3, 3, 0);
  tile_b_kernel<<<512, 256, 0, stream>>>(Bbase, scales, out + 98041856ull, 64, 1024, 2, 2, 1, 1);
  tile_b_kernel<<<2048, 256, 0, stream>>>(Bbase, scales, out + 102236160ull, 64, 11008, 8, 2, 1, 4);
}